// Round 9
// baseline (7065.946 us; speedup 1.0000x reference)
//
#include <hip/hip_runtime.h>
#include <hip/hip_bf16.h>
#include <hip/hip_cooperative_groups.h>

namespace cg = cooperative_groups;

#define SEQ 512
#define BATCH 128
#define INP 512
#define HID 1024
#define CLASSES 1000
#define NKX (INP / 32)        // 16
#define NKH (HID / 32)        // 32

#define NBLK 256
#define NTHR 256              // 4 waves, M=32 per wave, N=16 per block
#define BJ 4                  // h-columns per block
#define G4H (4 * HID)

typedef float f32x4 __attribute__((ext_vector_type(4)));
typedef short bf16x8 __attribute__((ext_vector_type(8)));

__device__ __forceinline__ short f2bf16s(float f) {
    __hip_bfloat16 h = __float2bfloat16(f);
    return __builtin_bit_cast(short, h);
}
__device__ __forceinline__ float sigmoidf_(float x) {
    return 1.0f / (1.0f + __expf(-x));
}
__device__ __forceinline__ float tanhf_(float x) {
    x = fminf(fmaxf(x, -15.0f), 15.0f);
    float e = __expf(2.0f * x);
    return (e - 1.0f) / (e + 1.0f);
}

// ================= K1: fp32 -> bf16 convert (x, optionally W_ih) =========
#define XCH (SEQ * BATCH * INP / 8)
#define WCH (4 * HID * INP / 8)
__global__ __launch_bounds__(256)
void convert_bf16(const float* __restrict__ x, const float* __restrict__ W_ih,
                  unsigned short* __restrict__ xbf, unsigned short* __restrict__ Wbf,
                  int do_w) {
    const size_t total = XCH + (do_w ? WCH : 0);
    for (size_t c = (size_t)blockIdx.x * blockDim.x + threadIdx.x; c < total;
         c += (size_t)gridDim.x * blockDim.x) {
        const float* src; unsigned short* dst;
        if (c < XCH) { src = x + c * 8;            dst = xbf + c * 8; }
        else         { src = W_ih + (c - XCH) * 8; dst = Wbf + (c - XCH) * 8; }
        const float4 a = *(const float4*)src;
        const float4 b = *(const float4*)(src + 4);
        bf16x8 v;
        v[0] = f2bf16s(a.x); v[1] = f2bf16s(a.y);
        v[2] = f2bf16s(a.z); v[3] = f2bf16s(a.w);
        v[4] = f2bf16s(b.x); v[5] = f2bf16s(b.y);
        v[6] = f2bf16s(b.z); v[7] = f2bf16s(b.w);
        *(bf16x8*)dst = v;
    }
}

// ================= K2: xproj in K3-consumer order (fp32) ==================
// Consumer (256 blk x 4 wave x 64 lane) reads ONE 32B chunk per step:
//   addr(floats) = (((t*256 + bidC)*4 + waveC)*64 + laneC)*8 + mi*4 + r
// where laneC = lgrp*16 + nloc, nloc = gate*4 + (hcol&3), bidC = hcol>>2,
// and (waveC, mi, lgrp, r) decompose the batch row m = w*32+mi*16+lgrp*4+r.
__global__ __launch_bounds__(256)
void xproj_gemm(const unsigned short* __restrict__ xbf,
                const unsigned short* __restrict__ Wbf,
                float* __restrict__ xpp) {
    const int tid = threadIdx.x;
    const int w = tid >> 6;
    const int lane = tid & 63;
    const int ln15 = lane & 15;
    const int lgrp = lane >> 4;
    const int k8 = lgrp * 8;
    const int bx = blockIdx.x;                    // == timestep t (128 rows)
    const int m0 = bx * 128 + w * 32 + ln15;
    const int n0 = blockIdx.y * 128 + ln15;

    f32x4 acc[2][8];
    #pragma unroll
    for (int i = 0; i < 2; i++)
        #pragma unroll
        for (int j = 0; j < 8; j++) acc[i][j] = (f32x4){0.f, 0.f, 0.f, 0.f};

    #pragma unroll 4
    for (int kt = 0; kt < INP / 32; kt++) {
        const int k = kt * 32 + k8;
        bf16x8 a0 = *(const bf16x8*)(xbf + (size_t)m0 * INP + k);
        bf16x8 a1 = *(const bf16x8*)(xbf + (size_t)(m0 + 16) * INP + k);
        #pragma unroll
        for (int nt = 0; nt < 8; nt++) {
            bf16x8 b = *(const bf16x8*)(Wbf + (size_t)(n0 + nt * 16) * INP + k);
            acc[0][nt] = __builtin_amdgcn_mfma_f32_16x16x32_bf16(a0, b, acc[0][nt], 0, 0, 0);
            acc[1][nt] = __builtin_amdgcn_mfma_f32_16x16x32_bf16(a1, b, acc[1][nt], 0, 0, 0);
        }
    }
    // C/D: row_in_tile = lgrp*4 + r, col = ln15
    #pragma unroll
    for (int nt = 0; nt < 8; nt++) {
        const int nG   = blockIdx.y * 128 + nt * 16 + ln15;   // global gate row
        const int g    = nG >> 10;
        const int colh = nG & 1023;
        const int bidC = colh >> 2;
        const int nloc = g * 4 + (colh & 3);
        #pragma unroll
        for (int mi = 0; mi < 2; mi++) {
            size_t base = ((((size_t)bx * NBLK + bidC) * 4 + w) * 64
                           + (size_t)(lgrp * 16 + nloc)) * 8 + mi * 4;
            *(float4*)(xpp + base) = *(float4*)&acc[mi][nt];
        }
    }
}

// ================= K3: recurrent loop (cooperative) =======================
__device__ __forceinline__ void bar_signal(unsigned* flags, int bid, unsigned val) {
    __hip_atomic_store(&flags[bid], val, __ATOMIC_RELAXED,
                       __HIP_MEMORY_SCOPE_AGENT);
}
// wave0 polls all 256 flags (4/lane); then acquire-inv so normal loads see h
__device__ __forceinline__ void bar_wait_all(const unsigned* flags, int lane,
                                             unsigned want) {
    for (;;) {
        unsigned ok = 1u;
        #pragma unroll
        for (int i = 0; i < 4; i++) {
            unsigned f = __hip_atomic_load(&flags[lane + 64 * i], __ATOMIC_RELAXED,
                                           __HIP_MEMORY_SCOPE_AGENT);
            ok &= (unsigned)(f >= want);
        }
        if (__all(ok)) break;
        __builtin_amdgcn_s_sleep(1);
    }
    __builtin_amdgcn_fence(__ATOMIC_ACQUIRE, "agent");
}

__global__ __launch_bounds__(NTHR)
void lstm_fused(const float* __restrict__ x,
                const float* __restrict__ W_ih,
                const float* __restrict__ W_hh,
                const float* __restrict__ b_ih,
                const float* __restrict__ b_hh,
                const float* __restrict__ W_fc,
                const float* __restrict__ b_fc,
                float* __restrict__ out,
                unsigned short* __restrict__ h0,
                unsigned short* __restrict__ h1,
                unsigned short* __restrict__ xbf,
                const float* __restrict__ xpp,
                int use_xbf, int use_xp,
                unsigned* __restrict__ flags)
{
    // W_hh slice in MFMA-fragment order [kt][lane][8] (+16 x-kt in fallback)
    __shared__ short W_sw[48 * 64 * 8];        // 49152 B (32 used when use_xp)
    __shared__ float gw[4][32][17];            // wave-private transpose, 8704 B

    const int tid = threadIdx.x;
    const int bid = blockIdx.x;
    const int j0 = bid * BJ;

    // ---------------- one-time init ----------------
    // h-part weights: kt 0..31
    for (int f = tid; f < NKH * 64; f += NTHR) {       // 8 iters
        const int ln = f & 63;
        const int kt = f >> 6;
        const int nloc = ln & 15;
        const int rg = (nloc >> 2) * HID + j0 + (nloc & 3);
        const int kbase = kt * 32 + (ln >> 4) * 8;
        short tmp[8];
        #pragma unroll
        for (int j = 0; j < 8; j++)
            tmp[j] = f2bf16s(W_hh[(size_t)rg * HID + kbase + j]);
        *(bf16x8*)&W_sw[(size_t)f * 8] = *(bf16x8*)tmp;
    }
    if (!use_xp) {                                     // x-part weights: kt 32..47
        for (int f = tid; f < NKX * 64; f += NTHR) {
            const int ln = f & 63;
            const int kt = f >> 6;
            const int nloc = ln & 15;
            const int rg = (nloc >> 2) * HID + j0 + (nloc & 3);
            const int kbase = kt * 32 + (ln >> 4) * 8;
            short tmp[8];
            #pragma unroll
            for (int j = 0; j < 8; j++)
                tmp[j] = f2bf16s(W_ih[(size_t)rg * INP + kbase + j]);
            *(bf16x8*)&W_sw[(size_t)(NKH * 64 + f) * 8] = *(bf16x8*)tmp;
        }
    }
    {   // zero h0: 65536 dwords over 65536 grid threads
        const unsigned g = (unsigned)bid * NTHR + tid;
        ((unsigned*)h0)[g] = 0u;
    }
    if (bid == 0) {
        for (int i = tid; i < NBLK; i += NTHR) flags[i] = 0u;
    }

    const int wave = tid >> 6;          // 0..3 -> M-block of 32 batch rows
    const int lane = tid & 63;
    const int ln15 = lane & 15;
    const int lgrp = lane >> 4;
    const int arow = wave * 32 + ln15;  // M-tile0 batch row (tile1: +16)
    const int k8 = lgrp * 8;

    // cell update: 2 cells/thread, own wave's rows (wave-private gw)
    const int crow = lane >> 1;              // local row 0..31
    const int jp   = lane & 1;               // col pair (2 cols each)
    const int bg   = wave * 32 + crow;       // global batch row
    float c_r[2] = {0.f, 0.f};
    float bias_r[2][4];
    #pragma unroll
    for (int jj = 0; jj < 2; jj++)
        #pragma unroll
        for (int g = 0; g < 4; g++) {
            const int r = g * HID + j0 + jp * 2 + jj;
            bias_r[jj][g] = b_ih[r] + b_hh[r];
        }

    __syncthreads();
    cg::this_grid().sync();   // publish zeros/xbf/xpp grid-wide

    const bf16x8* Wl = (const bf16x8*)W_sw + lane;   // + kt*64

    for (int t = 0; t < SEQ; t++) {
        const unsigned short* __restrict__ hp = (t & 1) ? h1 : h0;
        unsigned short* __restrict__ hcur     = (t & 1) ? h0 : h1;

        f32x4 acc00 = {0.f,0.f,0.f,0.f};   // M-tile0
        f32x4 acc10 = {0.f,0.f,0.f,0.f};   // M-tile1
        float4 xv0 = {0,0,0,0}, xv1 = {0,0,0,0};

        // ---- h-independent work BEFORE the wait ----
        if (use_xp) {
            const float* xvp = xpp + ((((size_t)t * NBLK + bid) * 4 + wave) * 64
                                      + (size_t)lane) * 8;
            xv0 = *(const float4*)xvp;          // M-tile0 contribution
            xv1 = *(const float4*)(xvp + 4);    // M-tile1 contribution
        } else if (use_xbf) {
            const unsigned short* xr =
                xbf + (size_t)t * (BATCH * INP) + (size_t)arow * INP + k8;
            #pragma unroll
            for (int kt = 0; kt < NKX; kt++) {
                bf16x8 a0 = *(const bf16x8*)(xr + kt * 32);
                bf16x8 a1 = *(const bf16x8*)(xr + 16 * INP + kt * 32);
                bf16x8 b  = Wl[(NKH + kt) * 64];
                acc00 = __builtin_amdgcn_mfma_f32_16x16x32_bf16(a0, b, acc00, 0, 0, 0);
                acc10 = __builtin_amdgcn_mfma_f32_16x16x32_bf16(a1, b, acc10, 0, 0, 0);
            }
        } else {
            const float* xr =
                x + (size_t)t * (BATCH * INP) + (size_t)arow * INP + k8;
            #pragma unroll
            for (int kt = 0; kt < NKX; kt++) {
                const float4 xa = *(const float4*)(xr + kt * 32);
                const float4 xb = *(const float4*)(xr + kt * 32 + 4);
                const float4 ya = *(const float4*)(xr + 16 * INP + kt * 32);
                const float4 yb = *(const float4*)(xr + 16 * INP + kt * 32 + 4);
                bf16x8 a0, a1;
                a0[0]=f2bf16s(xa.x); a0[1]=f2bf16s(xa.y); a0[2]=f2bf16s(xa.z); a0[3]=f2bf16s(xa.w);
                a0[4]=f2bf16s(xb.x); a0[5]=f2bf16s(xb.y); a0[6]=f2bf16s(xb.z); a0[7]=f2bf16s(xb.w);
                a1[0]=f2bf16s(ya.x); a1[1]=f2bf16s(ya.y); a1[2]=f2bf16s(ya.z); a1[3]=f2bf16s(ya.w);
                a1[4]=f2bf16s(yb.x); a1[5]=f2bf16s(yb.y); a1[6]=f2bf16s(yb.z); a1[7]=f2bf16s(yb.w);
                bf16x8 b = Wl[(NKH + kt) * 64];
                acc00 = __builtin_amdgcn_mfma_f32_16x16x32_bf16(a0, b, acc00, 0, 0, 0);
                acc10 = __builtin_amdgcn_mfma_f32_16x16x32_bf16(a1, b, acc10, 0, 0, 0);
            }
        }

        // ---- wait for h_t, then minimal h-GEMM ----
        if (tid < 64) bar_wait_all(flags, lane, (unsigned)t);
        __syncthreads();

        {
            const unsigned short* hr = hp + (size_t)arow * HID + k8;
            #pragma unroll
            for (int kt = 0; kt < NKH; kt++) {
                bf16x8 a0 = *(const bf16x8*)(hr + kt * 32);
                bf16x8 a1 = *(const bf16x8*)(hr + 16 * HID + kt * 32);
                bf16x8 b  = Wl[kt * 64];
                acc00 = __builtin_amdgcn_mfma_f32_16x16x32_bf16(a0, b, acc00, 0, 0, 0);
                acc10 = __builtin_amdgcn_mfma_f32_16x16x32_bf16(a1, b, acc10, 0, 0, 0);
            }
        }
        acc00[0] += xv0.x; acc00[1] += xv0.y; acc00[2] += xv0.z; acc00[3] += xv0.w;
        acc10[0] += xv1.x; acc10[1] += xv1.y; acc10[2] += xv1.z; acc10[3] += xv1.w;

        // ---- wave-private transpose (C/D: row=lgrp*4+r, col=ln15) ----
        {
            const int r0 = lgrp * 4;
            #pragma unroll
            for (int r = 0; r < 4; r++) {
                gw[wave][r0 + r][ln15]      = acc00[r];
                gw[wave][16 + r0 + r][ln15] = acc10[r];
            }
        }

        // ---- cell update: 2 cells/thread + one 4B write-through store ----
        {
            unsigned pack = 0;
            #pragma unroll
            for (int jj = 0; jj < 2; jj++) {
                const int c = jp * 2 + jj;
                float ig = gw[wave][crow][c]      + bias_r[jj][0];
                float fg = gw[wave][crow][4 + c]  + bias_r[jj][1];
                float gg = gw[wave][crow][8 + c]  + bias_r[jj][2];
                float og = gw[wave][crow][12 + c] + bias_r[jj][3];
                ig = sigmoidf_(ig); fg = sigmoidf_(fg);
                gg = tanhf_(gg);    og = sigmoidf_(og);
                float cc = fg * c_r[jj] + ig * gg;
                c_r[jj] = cc;
                float h = og * tanhf_(cc);
                pack |= ((unsigned)(unsigned short)f2bf16s(h)) << (16 * jj);
            }
            __hip_atomic_store((unsigned*)(hcur + (size_t)bg * HID + j0 + jp * 2),
                               pack, __ATOMIC_RELAXED, __HIP_MEMORY_SCOPE_AGENT);
        }
        asm volatile("s_waitcnt vmcnt(0)" ::: "memory");  // h acked at L3
        __syncthreads();
        if (tid == 0) bar_signal(flags, bid, (unsigned)(t + 1));
    }

    cg::this_grid().sync();   // release h_final + acquire for FC

    // ---- FC epilogue: 128000 outputs over 65536 threads (2 iters) ----
    for (unsigned idx = (unsigned)bid * NTHR + tid; idx < BATCH * CLASSES;
         idx += (unsigned)NBLK * NTHR) {
        const int b   = idx / CLASSES;
        const int cls = idx % CLASSES;
        const unsigned short* hrow = h0 + (size_t)b * HID;   // SEQ even
        const float* wrow = W_fc + (size_t)cls * HID;
        float acc = 0.f;
        #pragma unroll 4
        for (int k = 0; k < HID; k += 8) {
            bf16x8 hv = *(const bf16x8*)(hrow + k);
            float4 w0 = *(const float4*)(wrow + k);
            float4 w1 = *(const float4*)(wrow + k + 4);
            union { unsigned u; float f; } e;
            float s = 0.f;
            e.u = ((unsigned)(unsigned short)hv[0]) << 16; s += e.f * w0.x;
            e.u = ((unsigned)(unsigned short)hv[1]) << 16; s += e.f * w0.y;
            e.u = ((unsigned)(unsigned short)hv[2]) << 16; s += e.f * w0.z;
            e.u = ((unsigned)(unsigned short)hv[3]) << 16; s += e.f * w0.w;
            e.u = ((unsigned)(unsigned short)hv[4]) << 16; s += e.f * w1.x;
            e.u = ((unsigned)(unsigned short)hv[5]) << 16; s += e.f * w1.y;
            e.u = ((unsigned)(unsigned short)hv[6]) << 16; s += e.f * w1.z;
            e.u = ((unsigned)(unsigned short)hv[7]) << 16; s += e.f * w1.w;
            acc += s;
        }
        out[idx] = acc + b_fc[cls];
    }
}

extern "C" void kernel_launch(void* const* d_in, const int* in_sizes, int n_in,
                              void* d_out, int out_size, void* d_ws, size_t ws_size,
                              hipStream_t stream) {
    const float* x    = (const float*)d_in[0];
    const float* W_ih = (const float*)d_in[1];
    const float* W_hh = (const float*)d_in[2];
    const float* b_ih = (const float*)d_in[3];
    const float* b_hh = (const float*)d_in[4];
    const float* W_fc = (const float*)d_in[5];
    const float* b_fc = (const float*)d_in[6];
    float* out = (float*)d_out;

    // ws layout: h0 | h1 | xbf(64MB) | Wbf(4MB) | xpp(1GB)
    const size_t OFF_H1   = (size_t)BATCH * HID * 2;
    const size_t OFF_XBF  = 2 * OFF_H1;
    const size_t XBF_B    = (size_t)SEQ * BATCH * INP * 2;
    const size_t OFF_WBF  = OFF_XBF + XBF_B;
    const size_t WBF_B    = (size_t)4 * HID * INP * 2;
    const size_t OFF_XPP  = OFF_WBF + WBF_B;
    const size_t XPP_B    = (size_t)SEQ * BATCH * G4H * 4;

    unsigned short* h0   = (unsigned short*)d_ws;
    unsigned short* h1   = (unsigned short*)((char*)d_ws + OFF_H1);
    unsigned short* xbf  = (unsigned short*)((char*)d_ws + OFF_XBF);
    unsigned short* Wbf  = (unsigned short*)((char*)d_ws + OFF_WBF);
    float*          xpp  = (float*)((char*)d_ws + OFF_XPP);

    int use_xbf = (ws_size >= OFF_XBF + XBF_B) ? 1 : 0;
    int use_xp  = (ws_size >= OFF_XPP + XPP_B) ? 1 : 0;

    if (use_xbf) {
        convert_bf16<<<dim3(2048), dim3(256), 0, stream>>>(x, W_ih, xbf, Wbf, use_xp);
    }
    if (use_xp) {
        xproj_gemm<<<dim3(512, 32), dim3(256), 0, stream>>>(xbf, Wbf, xpp);
    }

    unsigned* flags = (unsigned*)d_out;  // 256 words; overwritten by FC at end

    void* args[] = {&x, &W_ih, &W_hh, &b_ih, &b_hh, &W_fc, &b_fc, &out,
                    &h0, &h1, &xbf, &xpp, &use_xbf, &use_xp, &flags};
    hipLaunchCooperativeKernel((void*)lstm_fused, dim3(NBLK), dim3(NTHR),
                               args, 0, stream);
}

// Round 10
// 7043.694 us; speedup vs baseline: 1.0032x; 1.0032x over previous
//
#include <hip/hip_runtime.h>
#include <hip/hip_bf16.h>
#include <hip/hip_cooperative_groups.h>

namespace cg = cooperative_groups;

#define SEQ 512
#define BATCH 128
#define INP 512
#define HID 1024
#define CLASSES 1000
#define NKX (INP / 32)        // 16
#define NKH (HID / 32)        // 32
#define G4H (4 * HID)

// ---- new grouped kernel geometry ----
#define NBLK 256
#define NTHR 256              // 4 waves
#define NGRP 4                // independent batch groups
#define GBLK 64               // blocks per group
#define GROWS 32              // batch rows per group
#define NCOL 16               // h-cols per block
#define GRP_W ((size_t)512 * GROWS * HID)   // ring ushorts per group

typedef float f32x4 __attribute__((ext_vector_type(4)));
typedef short bf16x8 __attribute__((ext_vector_type(8)));

__device__ __forceinline__ short f2bf16s(float f) {
    __hip_bfloat16 h = __float2bfloat16(f);
    return __builtin_bit_cast(short, h);
}
__device__ __forceinline__ float sigmoidf_(float x) {
    return 1.0f / (1.0f + __expf(-x));
}
__device__ __forceinline__ float tanhf_(float x) {
    x = fminf(fmaxf(x, -15.0f), 15.0f);
    float e = __expf(2.0f * x);
    return (e - 1.0f) / (e + 1.0f);
}
__device__ __forceinline__ int permbuf(int t) { return (t * 197) & 511; }

// ================= K1: fp32 -> bf16 convert (x, W_ih) =====================
#define XCH (SEQ * BATCH * INP / 8)
#define WCH (4 * HID * INP / 8)
__global__ __launch_bounds__(256)
void convert_bf16(const float* __restrict__ x, const float* __restrict__ W_ih,
                  unsigned short* __restrict__ xbf, unsigned short* __restrict__ Wbf,
                  int do_w) {
    const size_t total = XCH + (do_w ? WCH : 0);
    for (size_t c = (size_t)blockIdx.x * blockDim.x + threadIdx.x; c < total;
         c += (size_t)gridDim.x * blockDim.x) {
        const float* src; unsigned short* dst;
        if (c < XCH) { src = x + c * 8;            dst = xbf + c * 8; }
        else         { src = W_ih + (c - XCH) * 8; dst = Wbf + (c - XCH) * 8; }
        const float4 a = *(const float4*)src;
        const float4 b = *(const float4*)(src + 4);
        bf16x8 v;
        v[0] = f2bf16s(a.x); v[1] = f2bf16s(a.y);
        v[2] = f2bf16s(a.z); v[3] = f2bf16s(a.w);
        v[4] = f2bf16s(b.x); v[5] = f2bf16s(b.y);
        v[6] = f2bf16s(b.z); v[7] = f2bf16s(b.w);
        *(bf16x8*)dst = v;
    }
}

// ================= K2: xproj in consumer order (fp32) =====================
// mode 1 (grouped): addr = (((t*256 + bid)*4 + gate)*64 + lgrp*16+c)*8 + mi*4 + r
//   with bid = g*64 + e, g = batch>>5, e = hcol>>4, c = hcol&15.
// mode 0 (v9):      addr = (((t*256 + bidC)*4 + w)*64 + lgrp*16+nloc)*8 + mi*4 + r
//   with bidC = hcol>>2, nloc = gate*4 + (hcol&3).
__global__ __launch_bounds__(256)
void xproj_gemm(const unsigned short* __restrict__ xbf,
                const unsigned short* __restrict__ Wbf,
                float* __restrict__ xpp, int mode) {
    const int tid = threadIdx.x;
    const int w = tid >> 6;
    const int lane = tid & 63;
    const int ln15 = lane & 15;
    const int lgrp = lane >> 4;
    const int k8 = lgrp * 8;
    const int bx = blockIdx.x;                    // timestep t
    const int m0 = bx * 128 + w * 32 + ln15;
    const int n0 = blockIdx.y * 128 + ln15;

    f32x4 acc[2][8];
    #pragma unroll
    for (int i = 0; i < 2; i++)
        #pragma unroll
        for (int j = 0; j < 8; j++) acc[i][j] = (f32x4){0.f, 0.f, 0.f, 0.f};

    #pragma unroll 4
    for (int kt = 0; kt < INP / 32; kt++) {
        const int k = kt * 32 + k8;
        bf16x8 a0 = *(const bf16x8*)(xbf + (size_t)m0 * INP + k);
        bf16x8 a1 = *(const bf16x8*)(xbf + (size_t)(m0 + 16) * INP + k);
        #pragma unroll
        for (int nt = 0; nt < 8; nt++) {
            bf16x8 b = *(const bf16x8*)(Wbf + (size_t)(n0 + nt * 16) * INP + k);
            acc[0][nt] = __builtin_amdgcn_mfma_f32_16x16x32_bf16(a0, b, acc[0][nt], 0, 0, 0);
            acc[1][nt] = __builtin_amdgcn_mfma_f32_16x16x32_bf16(a1, b, acc[1][nt], 0, 0, 0);
        }
    }
    // C/D: m_in_tile = lgrp*4 + r, n = ln15. batch row = m0-range, g = w.
    #pragma unroll
    for (int nt = 0; nt < 8; nt++) {
        const int nG   = blockIdx.y * 128 + nt * 16 + ln15;
        const int gate = nG >> 10;
        const int colh = nG & 1023;
        #pragma unroll
        for (int mi = 0; mi < 2; mi++) {
            size_t base;
            if (mode) {
                const int bidT = w * GBLK + (colh >> 4);
                base = ((((size_t)bx * NBLK + bidT) * 4 + gate) * 64
                        + (size_t)(lgrp * 16 + (colh & 15))) * 8 + mi * 4;
            } else {
                const int bidC = colh >> 2;
                const int nloc = gate * 4 + (colh & 3);
                base = ((((size_t)bx * NBLK + bidC) * 4 + w) * 64
                        + (size_t)(lgrp * 16 + nloc)) * 8 + mi * 4;
            }
            *(float4*)(xpp + base) = *(float4*)&acc[mi][nt];
        }
    }
}

// ================= K3a: grouped recurrent kernel ==========================
__global__ __launch_bounds__(NTHR)
void lstm_groups(const float* __restrict__ W_hh,
                 const float* __restrict__ b_ih,
                 const float* __restrict__ b_hh,
                 const float* __restrict__ W_fc,
                 const float* __restrict__ b_fc,
                 float* __restrict__ out,
                 const float* __restrict__ xpp,
                 unsigned short* __restrict__ ring,
                 unsigned* __restrict__ flags)
{
    __shared__ short W_sw[4 * 32 * 64 * 8];    // 131072 B, [w][kt][lane][8]
    __shared__ float gw[2][64][33];            // parity x [nloc][m], 16896 B

    const int tid = threadIdx.x;
    const int bid = blockIdx.x;
    const int g   = bid >> 6;                  // group 0..3
    const int e   = bid & 63;                  // block in group (h-col slice)

    const int wave = tid >> 6;
    const int lane = tid & 63;
    const int ln15 = lane & 15;
    const int lgrp = lane >> 4;

    // ---- one-time init: W_hh slice -> LDS in fragment order ----
    for (int f = tid; f < 4 * 32 * 64; f += NTHR) {    // 32 iters
        const int ln = f & 63;
        const int kt = (f >> 6) & 31;
        const int w  = f >> 11;
        const int rg = w * HID + e * NCOL + (ln & 15); // gate row
        const int k  = kt * 32 + (ln >> 4) * 8;
        short tmp[8];
        #pragma unroll
        for (int j = 0; j < 8; j++)
            tmp[j] = f2bf16s(W_hh[(size_t)rg * HID + k + j]);
        *(bf16x8*)&W_sw[(size_t)f * 8] = *(bf16x8*)tmp;
    }
    {   // zero ring buffer0 of all groups: 65536 dwords over 65536 threads
        const unsigned gt = (unsigned)bid * NTHR + tid;
        const unsigned grp = gt >> 14, off = gt & 16383;
        __hip_atomic_store((unsigned*)ring + (size_t)grp * (GRP_W / 2) + off,
                           0u, __ATOMIC_RELAXED, __HIP_MEMORY_SCOPE_AGENT);
    }
    if (bid == 0) {
        for (int i = tid; i < 16384; i += NTHR) flags[i] = 0u;
    }

    // cell-update assignment: m = tid>>3 (0..31), col pair cp = (tid&7)*2
    const int cm = tid >> 3;
    const int cp = (tid & 7) * 2;
    float c_r[2] = {0.f, 0.f};
    float bias_r[2][4];
    #pragma unroll
    for (int jj = 0; jj < 2; jj++)
        #pragma unroll
        for (int g4 = 0; g4 < 4; g4++) {
            const int r = g4 * HID + e * NCOL + cp + jj;
            bias_r[jj][g4] = b_ih[r] + b_hh[r];
        }

    __syncthreads();
    cg::this_grid().sync();   // publish ring zeros / flags / xpp grid-wide

    const bf16x8* Wb = (const bf16x8*)W_sw + (size_t)wave * 32 * 64 + lane;
    unsigned short* const ringG = ring + (size_t)g * GRP_W;
    unsigned* const flagG = flags + g * 1024;

    for (int t = 0; t < SEQ; t++) {
        const unsigned short* hb = ringG + (size_t)permbuf(t) * (GROWS * HID);
        unsigned short* hn       = ringG + (size_t)permbuf(t + 1) * (GROWS * HID);

        // xpp prefetch (independent of h)
        const float* xvp = xpp + ((((size_t)t * NBLK + bid) * 4 + wave) * 64
                                  + (size_t)lane) * 8;
        const float4 xv0 = *(const float4*)xvp;
        const float4 xv1 = *(const float4*)(xvp + 4);

        // ---- wait for all 64 producers of this group (ring: no fence) ----
        {
            const unsigned* fp = &flagG[lane * 16];
            for (;;) {
                unsigned f = __hip_atomic_load(fp, __ATOMIC_RELAXED,
                                               __HIP_MEMORY_SCOPE_AGENT);
                if (__all(f >= (unsigned)t)) break;
                __builtin_amdgcn_s_sleep(1);
            }
            asm volatile("" ::: "memory");
        }

        // ---- h-GEMM: M=32 (2 tiles), N=16 (this wave's slice), K=1024 ----
        f32x4 acc0 = {0.f,0.f,0.f,0.f};
        f32x4 acc1 = {0.f,0.f,0.f,0.f};
        {
            const unsigned short* hr0 = hb + (size_t)ln15 * HID + lgrp * 8;
            const unsigned short* hr1 = hr0 + 16 * HID;
            #pragma unroll
            for (int kt = 0; kt < NKH; kt++) {
                bf16x8 a0 = *(const bf16x8*)(hr0 + kt * 32);
                bf16x8 a1 = *(const bf16x8*)(hr1 + kt * 32);
                bf16x8 b  = Wb[kt * 64];
                acc0 = __builtin_amdgcn_mfma_f32_16x16x32_bf16(a0, b, acc0, 0, 0, 0);
                acc1 = __builtin_amdgcn_mfma_f32_16x16x32_bf16(a1, b, acc1, 0, 0, 0);
            }
        }
        acc0[0] += xv0.x; acc0[1] += xv0.y; acc0[2] += xv0.z; acc0[3] += xv0.w;
        acc1[0] += xv1.x; acc1[1] += xv1.y; acc1[2] += xv1.z; acc1[3] += xv1.w;

        // ---- transpose to LDS (C/D: m=lgrp*4+r, n=ln15), parity buffer ----
        {
            const int par = t & 1;
            const int nr = wave * 16 + ln15;
            #pragma unroll
            for (int r = 0; r < 4; r++) {
                gw[par][nr][lgrp * 4 + r]      = acc0[r];
                gw[par][nr][16 + lgrp * 4 + r] = acc1[r];
            }
        }
        __syncthreads();

        // ---- cell update: 2 cells/thread + one 4B write-through store ----
        {
            const int par = t & 1;
            unsigned pack = 0;
            #pragma unroll
            for (int jj = 0; jj < 2; jj++) {
                const int col = cp + jj;
                float ig = gw[par][col][cm]      + bias_r[jj][0];
                float fg = gw[par][16 + col][cm] + bias_r[jj][1];
                float gg = gw[par][32 + col][cm] + bias_r[jj][2];
                float og = gw[par][48 + col][cm] + bias_r[jj][3];
                ig = sigmoidf_(ig); fg = sigmoidf_(fg);
                gg = tanhf_(gg);    og = sigmoidf_(og);
                float cc = fg * c_r[jj] + ig * gg;
                c_r[jj] = cc;
                float h = og * tanhf_(cc);
                pack |= ((unsigned)(unsigned short)f2bf16s(h)) << (16 * jj);
            }
            __hip_atomic_store((unsigned*)(hn + (size_t)cm * HID + e * NCOL + cp),
                               pack, __ATOMIC_RELAXED, __HIP_MEMORY_SCOPE_AGENT);
        }
        asm volatile("s_waitcnt vmcnt(0)" ::: "memory");   // stores acked at L3
        __syncthreads();                                    // all threads acked
        if (tid == 0)
            __hip_atomic_store(&flagG[e * 16], (unsigned)(t + 1),
                               __ATOMIC_RELAXED, __HIP_MEMORY_SCOPE_AGENT);
    }

    cg::this_grid().sync();   // full release/acquire before epilogue

    // ---- FC epilogue: h_last in ring buffer permbuf(512)=0 of each group ----
    for (unsigned idx = (unsigned)bid * NTHR + tid; idx < BATCH * CLASSES;
         idx += (unsigned)NBLK * NTHR) {
        const int b   = idx / CLASSES;
        const int cls = idx % CLASSES;
        const unsigned short* hrow = ring + (size_t)(b >> 5) * GRP_W
                                          + (size_t)(b & 31) * HID;
        const float* wrow = W_fc + (size_t)cls * HID;
        float acc = 0.f;
        #pragma unroll 4
        for (int k = 0; k < HID; k += 8) {
            bf16x8 hv = *(const bf16x8*)(hrow + k);
            float4 w0 = *(const float4*)(wrow + k);
            float4 w1 = *(const float4*)(wrow + k + 4);
            union { unsigned u; float f; } ee;
            float s = 0.f;
            ee.u = ((unsigned)(unsigned short)hv[0]) << 16; s += ee.f * w0.x;
            ee.u = ((unsigned)(unsigned short)hv[1]) << 16; s += ee.f * w0.y;
            ee.u = ((unsigned)(unsigned short)hv[2]) << 16; s += ee.f * w0.z;
            ee.u = ((unsigned)(unsigned short)hv[3]) << 16; s += ee.f * w0.w;
            ee.u = ((unsigned)(unsigned short)hv[4]) << 16; s += ee.f * w1.x;
            ee.u = ((unsigned)(unsigned short)hv[5]) << 16; s += ee.f * w1.y;
            ee.u = ((unsigned)(unsigned short)hv[6]) << 16; s += ee.f * w1.z;
            ee.u = ((unsigned)(unsigned short)hv[7]) << 16; s += ee.f * w1.w;
            acc += s;
        }
        out[idx] = acc + b_fc[cls];
    }
}

// ================= K3b: v9 fallback (proven) ==============================
__device__ __forceinline__ void bar_signal9(unsigned* flags, int bid, unsigned val) {
    __hip_atomic_store(&flags[bid], val, __ATOMIC_RELAXED,
                       __HIP_MEMORY_SCOPE_AGENT);
}
__device__ __forceinline__ void bar_wait9(const unsigned* flags, int lane,
                                          unsigned want) {
    for (;;) {
        unsigned ok = 1u;
        #pragma unroll
        for (int i = 0; i < 4; i++) {
            unsigned f = __hip_atomic_load(&flags[lane + 64 * i], __ATOMIC_RELAXED,
                                           __HIP_MEMORY_SCOPE_AGENT);
            ok &= (unsigned)(f >= want);
        }
        if (__all(ok)) break;
        __builtin_amdgcn_s_sleep(1);
    }
    __builtin_amdgcn_fence(__ATOMIC_ACQUIRE, "agent");
}

__global__ __launch_bounds__(256)
void lstm_fused_v9(const float* __restrict__ x,
                   const float* __restrict__ W_ih,
                   const float* __restrict__ W_hh,
                   const float* __restrict__ b_ih,
                   const float* __restrict__ b_hh,
                   const float* __restrict__ W_fc,
                   const float* __restrict__ b_fc,
                   float* __restrict__ out,
                   unsigned short* __restrict__ h0,
                   unsigned short* __restrict__ h1,
                   unsigned short* __restrict__ xbf,
                   const float* __restrict__ xpp,
                   int use_xbf, int use_xp,
                   unsigned* __restrict__ flags)
{
    __shared__ short W_sw[48 * 64 * 8];
    __shared__ float gw[4][32][17];

    const int tid = threadIdx.x;
    const int bid = blockIdx.x;
    const int j0 = bid * 4;

    for (int f = tid; f < NKH * 64; f += 256) {
        const int ln = f & 63;
        const int kt = f >> 6;
        const int nloc = ln & 15;
        const int rg = (nloc >> 2) * HID + j0 + (nloc & 3);
        const int kbase = kt * 32 + (ln >> 4) * 8;
        short tmp[8];
        #pragma unroll
        for (int j = 0; j < 8; j++)
            tmp[j] = f2bf16s(W_hh[(size_t)rg * HID + kbase + j]);
        *(bf16x8*)&W_sw[(size_t)f * 8] = *(bf16x8*)tmp;
    }
    if (!use_xp) {
        for (int f = tid; f < NKX * 64; f += 256) {
            const int ln = f & 63;
            const int kt = f >> 6;
            const int nloc = ln & 15;
            const int rg = (nloc >> 2) * HID + j0 + (nloc & 3);
            const int kbase = kt * 32 + (ln >> 4) * 8;
            short tmp[8];
            #pragma unroll
            for (int j = 0; j < 8; j++)
                tmp[j] = f2bf16s(W_ih[(size_t)rg * INP + kbase + j]);
            *(bf16x8*)&W_sw[(size_t)(NKH * 64 + f) * 8] = *(bf16x8*)tmp;
        }
    }
    {
        const unsigned g = (unsigned)bid * 256 + tid;
        ((unsigned*)h0)[g] = 0u;
    }
    if (bid == 0) {
        for (int i = tid; i < 256; i += 256) flags[i] = 0u;
    }

    const int wave = tid >> 6;
    const int lane = tid & 63;
    const int ln15 = lane & 15;
    const int lgrp = lane >> 4;
    const int arow = wave * 32 + ln15;
    const int k8 = lgrp * 8;

    const int crow = lane >> 1;
    const int jp   = lane & 1;
    const int bg   = wave * 32 + crow;
    float c_r[2] = {0.f, 0.f};
    float bias_r[2][4];
    #pragma unroll
    for (int jj = 0; jj < 2; jj++)
        #pragma unroll
        for (int g = 0; g < 4; g++) {
            const int r = g * HID + j0 + jp * 2 + jj;
            bias_r[jj][g] = b_ih[r] + b_hh[r];
        }

    __syncthreads();
    cg::this_grid().sync();

    const bf16x8* Wl = (const bf16x8*)W_sw + lane;

    for (int t = 0; t < SEQ; t++) {
        const unsigned short* __restrict__ hp = (t & 1) ? h1 : h0;
        unsigned short* __restrict__ hcur     = (t & 1) ? h0 : h1;

        f32x4 acc00 = {0.f,0.f,0.f,0.f};
        f32x4 acc10 = {0.f,0.f,0.f,0.f};
        float4 xv0 = {0,0,0,0}, xv1 = {0,0,0,0};

        if (use_xp) {
            const float* xvp = xpp + ((((size_t)t * 256 + bid) * 4 + wave) * 64
                                      + (size_t)lane) * 8;
            xv0 = *(const float4*)xvp;
            xv1 = *(const float4*)(xvp + 4);
        } else if (use_xbf) {
            const unsigned short* xr =
                xbf + (size_t)t * (BATCH * INP) + (size_t)arow * INP + k8;
            #pragma unroll
            for (int kt = 0; kt < NKX; kt++) {
                bf16x8 a0 = *(const bf16x8*)(xr + kt * 32);
                bf16x8 a1 = *(const bf16x8*)(xr + 16 * INP + kt * 32);
                bf16x8 b  = Wl[(NKH + kt) * 64];
                acc00 = __builtin_amdgcn_mfma_f32_16x16x32_bf16(a0, b, acc00, 0, 0, 0);
                acc10 = __builtin_amdgcn_mfma_f32_16x16x32_bf16(a1, b, acc10, 0, 0, 0);
            }
        } else {
            const float* xr =
                x + (size_t)t * (BATCH * INP) + (size_t)arow * INP + k8;
            #pragma unroll
            for (int kt = 0; kt < NKX; kt++) {
                const float4 xa = *(const float4*)(xr + kt * 32);
                const float4 xb = *(const float4*)(xr + kt * 32 + 4);
                const float4 ya = *(const float4*)(xr + 16 * INP + kt * 32);
                const float4 yb = *(const float4*)(xr + 16 * INP + kt * 32 + 4);
                bf16x8 a0, a1;
                a0[0]=f2bf16s(xa.x); a0[1]=f2bf16s(xa.y); a0[2]=f2bf16s(xa.z); a0[3]=f2bf16s(xa.w);
                a0[4]=f2bf16s(xb.x); a0[5]=f2bf16s(xb.y); a0[6]=f2bf16s(xb.z); a0[7]=f2bf16s(xb.w);
                a1[0]=f2bf16s(ya.x); a1[1]=f2bf16s(ya.y); a1[2]=f2bf16s(ya.z); a1[3]=f2bf16s(ya.w);
                a1[4]=f2bf16s(yb.x); a1[5]=f2bf16s(yb.y); a1[6]=f2bf16s(yb.z); a1[7]=f2bf16s(yb.w);
                bf16x8 b = Wl[(NKH + kt) * 64];
                acc00 = __builtin_amdgcn_mfma_f32_16x16x32_bf16(a0, b, acc00, 0, 0, 0);
                acc10 = __builtin_amdgcn_mfma_f32_16x16x32_bf16(a1, b, acc10, 0, 0, 0);
            }
        }

        if (tid < 64) bar_wait9(flags, lane, (unsigned)t);
        __syncthreads();

        {
            const unsigned short* hr = hp + (size_t)arow * HID + k8;
            #pragma unroll
            for (int kt = 0; kt < NKH; kt++) {
                bf16x8 a0 = *(const bf16x8*)(hr + kt * 32);
                bf16x8 a1 = *(const bf16x8*)(hr + 16 * HID + kt * 32);
                bf16x8 b  = Wl[kt * 64];
                acc00 = __builtin_amdgcn_mfma_f32_16x16x32_bf16(a0, b, acc00, 0, 0, 0);
                acc10 = __builtin_amdgcn_mfma_f32_16x16x32_bf16(a1, b, acc10, 0, 0, 0);
            }
        }
        acc00[0] += xv0.x; acc00[1] += xv0.y; acc00[2] += xv0.z; acc00[3] += xv0.w;
        acc10[0] += xv1.x; acc10[1] += xv1.y; acc10[2] += xv1.z; acc10[3] += xv1.w;

        {
            const int r0 = lgrp * 4;
            #pragma unroll
            for (int r = 0; r < 4; r++) {
                gw[wave][r0 + r][ln15]      = acc00[r];
                gw[wave][16 + r0 + r][ln15] = acc10[r];
            }
        }
        {
            unsigned pack = 0;
            #pragma unroll
            for (int jj = 0; jj < 2; jj++) {
                const int c = jp * 2 + jj;
                float ig = gw[wave][crow][c]      + bias_r[jj][0];
                float fg = gw[wave][crow][4 + c]  + bias_r[jj][1];
                float gg = gw[wave][crow][8 + c]  + bias_r[jj][2];
                float og = gw[wave][crow][12 + c] + bias_r[jj][3];
                ig = sigmoidf_(ig); fg = sigmoidf_(fg);
                gg = tanhf_(gg);    og = sigmoidf_(og);
                float cc = fg * c_r[jj] + ig * gg;
                c_r[jj] = cc;
                float h = og * tanhf_(cc);
                pack |= ((unsigned)(unsigned short)f2bf16s(h)) << (16 * jj);
            }
            __hip_atomic_store((unsigned*)(hcur + (size_t)bg * HID + j0 + jp * 2),
                               pack, __ATOMIC_RELAXED, __HIP_MEMORY_SCOPE_AGENT);
        }
        asm volatile("s_waitcnt vmcnt(0)" ::: "memory");
        __syncthreads();
        if (tid == 0) bar_signal9(flags, bid, (unsigned)(t + 1));
    }

    cg::this_grid().sync();

    for (unsigned idx = (unsigned)bid * 256 + tid; idx < BATCH * CLASSES;
         idx += (unsigned)256 * 256) {
        const int b   = idx / CLASSES;
        const int cls = idx % CLASSES;
        const unsigned short* hrow = h0 + (size_t)b * HID;
        const float* wrow = W_fc + (size_t)cls * HID;
        float acc = 0.f;
        #pragma unroll 4
        for (int k = 0; k < HID; k += 8) {
            bf16x8 hv = *(const bf16x8*)(hrow + k);
            float4 w0 = *(const float4*)(wrow + k);
            float4 w1 = *(const float4*)(wrow + k + 4);
            union { unsigned u; float f; } ee;
            float s = 0.f;
            ee.u = ((unsigned)(unsigned short)hv[0]) << 16; s += ee.f * w0.x;
            ee.u = ((unsigned)(unsigned short)hv[1]) << 16; s += ee.f * w0.y;
            ee.u = ((unsigned)(unsigned short)hv[2]) << 16; s += ee.f * w0.z;
            ee.u = ((unsigned)(unsigned short)hv[3]) << 16; s += ee.f * w0.w;
            ee.u = ((unsigned)(unsigned short)hv[4]) << 16; s += ee.f * w1.x;
            ee.u = ((unsigned)(unsigned short)hv[5]) << 16; s += ee.f * w1.y;
            ee.u = ((unsigned)(unsigned short)hv[6]) << 16; s += ee.f * w1.z;
            ee.u = ((unsigned)(unsigned short)hv[7]) << 16; s += ee.f * w1.w;
            acc += s;
        }
        out[idx] = acc + b_fc[cls];
    }
}

extern "C" void kernel_launch(void* const* d_in, const int* in_sizes, int n_in,
                              void* d_out, int out_size, void* d_ws, size_t ws_size,
                              hipStream_t stream) {
    const float* x    = (const float*)d_in[0];
    const float* W_ih = (const float*)d_in[1];
    const float* W_hh = (const float*)d_in[2];
    const float* b_ih = (const float*)d_in[3];
    const float* b_hh = (const float*)d_in[4];
    const float* W_fc = (const float*)d_in[5];
    const float* b_fc = (const float*)d_in[6];
    float* out = (float*)d_out;

    // ws layout: h0 | h1 | xbf(64MB) | Wbf(4MB) | xpp(1GB) | ring(128MB)
    const size_t OFF_H1   = (size_t)BATCH * HID * 2;
    const size_t OFF_XBF  = 2 * OFF_H1;
    const size_t XBF_B    = (size_t)SEQ * BATCH * INP * 2;
    const size_t OFF_WBF  = OFF_XBF + XBF_B;
    const size_t WBF_B    = (size_t)4 * HID * INP * 2;
    const size_t OFF_XPP  = OFF_WBF + WBF_B;
    const size_t XPP_B    = (size_t)SEQ * BATCH * G4H * 4;
    const size_t OFF_RING = OFF_XPP + XPP_B;
    const size_t RING_B   = (size_t)NGRP * GRP_W * 2;     // 128 MB

    unsigned short* h0   = (unsigned short*)d_ws;
    unsigned short* h1   = (unsigned short*)((char*)d_ws + OFF_H1);
    unsigned short* xbf  = (unsigned short*)((char*)d_ws + OFF_XBF);
    unsigned short* Wbf  = (unsigned short*)((char*)d_ws + OFF_WBF);
    float*          xpp  = (float*)((char*)d_ws + OFF_XPP);
    unsigned short* ring = (unsigned short*)((char*)d_ws + OFF_RING);

    int use_xbf  = (ws_size >= OFF_XBF + XBF_B) ? 1 : 0;
    int use_xp   = (ws_size >= OFF_XPP + XPP_B) ? 1 : 0;
    int use_ring = (ws_size >= OFF_RING + RING_B) ? 1 : 0;
    const int grouped = (use_xp && use_ring) ? 1 : 0;

    if (use_xbf) {
        convert_bf16<<<dim3(2048), dim3(256), 0, stream>>>(x, W_ih, xbf, Wbf, use_xp);
    }
    if (use_xp) {
        xproj_gemm<<<dim3(512, 32), dim3(256), 0, stream>>>(xbf, Wbf, xpp, grouped);
    }

    unsigned* flags = (unsigned*)d_out;   // overwritten by FC at the end

    if (grouped) {
        void* args[] = {&W_hh, &b_ih, &b_hh, &W_fc, &b_fc, &out,
                        &xpp, &ring, &flags};
        hipLaunchCooperativeKernel((void*)lstm_groups, dim3(NBLK), dim3(NTHR),
                                   args, 0, stream);
    } else {
        void* args[] = {&x, &W_ih, &W_hh, &b_ih, &b_hh, &W_fc, &b_fc, &out,
                        &h0, &h1, &xbf, &xpp, &use_xbf, &use_xp, &flags};
        hipLaunchCooperativeKernel((void*)lstm_fused_v9, dim3(256), dim3(256),
                                   args, 0, stream);
    }
}